// Round 16
// baseline (319.186 us; speedup 1.0000x reference)
//
#include <hip/hip_runtime.h>
#include <hip/hip_bf16.h>

#define NN 16384
#define DD 256

typedef unsigned short u16;
typedef unsigned int u32;
typedef unsigned char u8;
typedef long i64;
typedef __attribute__((ext_vector_type(4))) float f32x4;
typedef __attribute__((ext_vector_type(4))) int i32x4;
typedef __attribute__((ext_vector_type(8))) int i32x8;

// ---------- kernel 1: fp8 e4m3 convert, LDS-transposed, all-coalesced ----------
// (verbatim from R6 -- measured clean, absmax 0.)
// A8 and B8 share ONE fragment-linear layout:
//   addr = pn<<15 | k2<<14 | r8<<11 | jj<<10 | qq<<8 | mm<<4 | u
//   holding fp8 of row (pn*128 + r8*16 + mm), kbyte (k2*128 + qq*32 + jj*16 + u).
__global__ __launch_bounds__(256) void prep_kernel(
        const float* __restrict__ img, const float* __restrict__ txt,
        u8* __restrict__ A8, u8* __restrict__ B8,
        float* __restrict__ zbuf /* s_row..s_col 32768 f */,
        float* __restrict__ out) {
    __shared__ u32 sA[16 * 65 + 8];
    __shared__ u32 sB[16 * 65 + 8];
    const int t = threadIdx.x, bi = blockIdx.x;            // bi = 16-row window
    const float4* ib = (const float4*)img + ((size_t)bi << 10);
    const float4* tb = (const float4*)txt + ((size_t)bi << 10);
    const float S = 1.44269504088896f;                     // log2(e) folded into A
    #pragma unroll
    for (int k = 0; k < 4; ++k) {
        const int idx = (k << 8) + t;                      // 0..1023 float4s
        const int row = idx >> 6, col = idx & 63;          // row 0..15, col 0..63
        float4 va = ib[idx];
        int pa = __builtin_amdgcn_cvt_pk_fp8_f32(va.x * S, va.y * S, 0, false);
        pa     = __builtin_amdgcn_cvt_pk_fp8_f32(va.z * S, va.w * S, pa, true);
        sA[row * 65 + col] = (u32)pa;
        float4 vb = tb[idx];
        int pb = __builtin_amdgcn_cvt_pk_fp8_f32(vb.x, vb.y, 0, false);
        pb     = __builtin_amdgcn_cvt_pk_fp8_f32(vb.z, vb.w, pb, true);
        sB[row * 65 + col] = (u32)pb;
    }
    __syncthreads();
    const int w = t >> 6, l = t & 63;
    const int k2 = w >> 1, jj = w & 1, qq = l >> 4, mm = l & 15;
    const int wb = mm * 65 + (k2 << 5) + (qq << 3) + (jj << 2);
    i32x4 oa = { (int)sA[wb], (int)sA[wb + 1], (int)sA[wb + 2], (int)sA[wb + 3] };
    i32x4 ob = { (int)sB[wb], (int)sB[wb + 1], (int)sB[wb + 2], (int)sB[wb + 3] };
    const size_t dst = ((size_t)(bi >> 3) << 15) + (k2 << 14) + ((size_t)(bi & 7) << 11)
                     + (jj << 10) + (qq << 8) + (mm << 4);
    *(i32x4*)(A8 + dst) = oa;
    *(i32x4*)(B8 + dst) = ob;
    const int gid = (bi << 8) + t;
    if (gid < 32768) zbuf[gid] = 0.0f;
    if (gid == 0) out[0] = 0.0f;
}

// ---------- kernel 2: MX-scaled fp8 GEMM + exp2 + row/col sum + diag ----------
// EXACT R14/R11 structure (best measured: gemm 78.2 us, 172 true regs/wave,
// 2 blocks/CU) with ONE change: __launch_bounds__(256, 3).
// The occupancy x registers matrix has one untried cell: 3 blocks/CU at this
// geometry. Wave pool ~2048 reg-units/CU (m69): 12 waves x 170 fits; we are
// at 172 -- TWO registers over the boundary. (256,3) targets <=170; the
// allocator typically remats addressing for a 2-4 reg shortfall (vs R9/R10
// which were 30-70 over -> spilled). If it fits: 12 waves/CU, 3 same-code
// waves/SIMD whose natural drift covers each other's MFMA<->VALU phases --
// R10's TLP mechanism without the tile-split that spilled it.
// Falsifiable: (a) fits -> VGPR<=~106, WRITE 17.47MB, Occ ~28%, gemm 60-70;
// (b) spills -> WRITE jumps -> revert R14, declare roofline;
// (c) fits+neutral -> intra-wave dependency-bound -> R14 is the roofline.
// (R14's s_sleep skew dropped: measured neutral.)
__global__ __launch_bounds__(256, 3) void gemm_lse_kernel(
        const u8* __restrict__ A8, const u8* __restrict__ B8,
        float* __restrict__ s_row, float* __restrict__ s_col,
        float* __restrict__ diag) {
    const int t = threadIdx.x;
    const int lane = t & 63;
    const int w = t >> 6;
    const int wr = w >> 1, wc = w & 1;
    const int q = lane >> 4, m = lane & 15;
    const int bi = blockIdx.x & 127;
    const int jg = blockIdx.x >> 7;
    const int row0 = bi << 7;

    // ---- A fragments direct from global (fragment-linear, coalesced) ----
    const u8* Aw = A8 + ((size_t)bi << 15) + ((size_t)lane << 4);
    i32x8 areg[2][4];
    #pragma unroll
    for (int k2 = 0; k2 < 2; ++k2)
        #pragma unroll
        for (int rb = 0; rb < 4; ++rb) {
            const u8* p = Aw + (k2 << 14) + (((wr << 2) + rb) << 11);
            i32x4 lo = *(const i32x4*)(p);
            i32x4 hi = *(const i32x4*)(p + 1024);
            areg[k2][rb] = __builtin_shufflevector(lo, hi, 0, 1, 2, 3, 4, 5, 6, 7);
        }

    const f32x4 fzero = {0.f, 0.f, 0.f, 0.f};
    f32x4 accA[4][2], accB[4][2];                 // half-tile acc banks (static)
    f32x4 rp[4] = {fzero, fzero, fzero, fzero};   // row partials
    float cpartT = 0.0f;                          // per-tile col partial

    const u8* Bw = B8 + (wc << 13) + ((size_t)lane << 4);

    i32x8 bf0, bf1, bf2, bf3;   // rotating one-fragment banks (slot i&3)

    // load fragment for slot ii (ii in 0..7: h=ii>>2, k2=(ii>>1)&1, cbl=ii&1)
    auto load_slot = [&](i32x8& bank, int jt_, int ii) {
        const int ct = (jg << 4) | ((jt_ + bi) & 15);
        const u8* pp = Bw + ((size_t)ct << 15) + ((ii >> 2) << 12)
                     + (((ii >> 1) & 1) << 14) + ((ii & 1) << 11);
        i32x4 lo = *(const i32x4*)(pp);
        i32x4 hi = *(const i32x4*)(pp + 1024);
        bank = __builtin_shufflevector(lo, hi, 0, 1, 2, 3, 4, 5, 6, 7);
    };

    // 4 MFMAs of one slot (k2_, cbl_ are call-site literals -> static acc idx)
    auto mfma_slot = [&](f32x4 (&acc)[4][2], const i32x8& bank, int k2_, int cbl_) {
        const f32x4 cinit = {-144.f, -144.f, -144.f, -144.f}; // exp2 bias in C
        if (k2_ == 0) {
            #pragma unroll
            for (int rb = 0; rb < 4; ++rb)
                acc[rb][cbl_] = __builtin_amdgcn_mfma_scale_f32_16x16x128_f8f6f4(
                    areg[0][rb], bank, cinit, 0, 0, 0, 127, 0, 127);
        } else {
            #pragma unroll
            for (int rb = 0; rb < 4; ++rb)
                acc[rb][cbl_] = __builtin_amdgcn_mfma_scale_f32_16x16x128_f8f6f4(
                    areg[1][rb], bank, acc[rb][cbl_], 0, 0, 0, 127, 0, 127);
        }
    };

    // epilogue for a finished half (diag, exp2, row/col partials)
    auto epilogue_half = [&](f32x4 (&acc)[4][2], int jt_, int h) {
        const int ct = (jg << 4) | ((jt_ + bi) & 15);
        if (bi == ct && wr == wc) {
            #pragma unroll
            for (int rb = 0; rb < 4; ++rb)
                if ((rb >> 1) == h) {
                    #pragma unroll
                    for (int r = 0; r < 4; ++r)
                        if (m == ((q << 2) | r))
                            diag[row0 + (wr << 6) + (rb << 4) + m] = acc[rb][rb & 1][r];
                }
        }
        #pragma unroll
        for (int rb = 0; rb < 4; ++rb)
            #pragma unroll
            for (int cb = 0; cb < 2; ++cb)
                #pragma unroll
                for (int r = 0; r < 4; ++r)
                    acc[rb][cb][r] = __builtin_amdgcn_exp2f(acc[rb][cb][r]);
        #pragma unroll
        for (int rb = 0; rb < 4; ++rb)
            rp[rb] += acc[rb][0] + acc[rb][1];
        #pragma unroll
        for (int cb = 0; cb < 2; ++cb) {
            f32x4 s = (acc[0][cb] + acc[1][cb]) + (acc[2][cb] + acc[3][cb]);
            float v = (s[0] + s[1]) + (s[2] + s[3]);
            v += __shfl_xor(v, 16, 64);
            v += __shfl_xor(v, 32, 64);
            if (q == ((h << 1) | cb)) cpartT = v;
        }
        if (h == 1) {
            const int col0 = ct << 7;
            atomicAdd(&s_col[col0 + (wc << 6) + (q << 4) + m], cpartT);
        }
    };

    // ---- rotating-prefetch main loop: load slot s+2 at slot s ----
    load_slot(bf0, 0, 0);
    load_slot(bf1, 0, 1);
    #pragma unroll 1
    for (int jt = 0; jt < 16; ++jt) {
        load_slot(bf2, jt, 2);  mfma_slot(accA, bf0, 0, 0);   // slot 0
        load_slot(bf3, jt, 3);  mfma_slot(accA, bf1, 0, 1);   // slot 1
        load_slot(bf0, jt, 4);  mfma_slot(accA, bf2, 1, 0);   // slot 2
        load_slot(bf1, jt, 5);  mfma_slot(accA, bf3, 1, 1);   // slot 3
        if (jt > 0) epilogue_half(accB, jt - 1, 1);
        load_slot(bf2, jt, 6);  mfma_slot(accB, bf0, 0, 0);   // slot 4
        load_slot(bf3, jt, 7);  mfma_slot(accB, bf1, 0, 1);   // slot 5
        if (jt < 15) load_slot(bf0, jt + 1, 0);
        mfma_slot(accB, bf2, 1, 0);                           // slot 6
        if (jt < 15) load_slot(bf1, jt + 1, 1);
        mfma_slot(accB, bf3, 1, 1);                           // slot 7
        epilogue_half(accA, jt, 0);
    }
    epilogue_half(accB, 15, 1);

    // ---- block-end row reduction ----
    float rout = 0.0f;
    #pragma unroll
    for (int rb = 0; rb < 4; ++rb)
        #pragma unroll
        for (int r = 0; r < 4; ++r) {
            float v = rp[rb][r];
            v += __shfl_xor(v, 1, 16);
            v += __shfl_xor(v, 2, 16);
            v += __shfl_xor(v, 4, 16);
            v += __shfl_xor(v, 8, 16);
            if (m == ((rb << 2) | r)) rout = v;
        }
    atomicAdd(&s_row[row0 + (wr << 6) + ((m >> 2) << 4) + (q << 2) + (m & 3)], rout);
}

// ---------- kernel 3: final reduce (64 blocks, 256 rows each) ----------
// diag is biased by -144; the +144 LSE un-bias cancels it exactly.
__global__ void final_kernel(const float* __restrict__ s_row, const float* __restrict__ s_col,
                             const float* __restrict__ diag, float* __restrict__ out) {
    __shared__ double red[256];
    int t = threadIdx.x;
    int i = blockIdx.x * 256 + t;
    double p = 0.5 * (double)(log2f(s_row[i]) + log2f(s_col[i])) - (double)diag[i];
    red[t] = p;
    __syncthreads();
    for (int s = 128; s > 0; s >>= 1) {
        if (t < s) red[t] += red[t + s];
        __syncthreads();
    }
    if (t == 0) atomicAdd(out, (float)(red[0] * 0.6931471805599453 / (double)NN));
}

// ---------- launch ----------
extern "C" void kernel_launch(void* const* d_in, const int* in_sizes, int n_in,
                              void* d_out, int out_size, void* d_ws, size_t ws_size,
                              hipStream_t stream) {
    const float* img = (const float*)d_in[0];
    const float* txt = (const float*)d_in[1];
    char* ws = (char*)d_ws;
    u8*    A8    = (u8*)ws;                                // 4 MB
    u8*    B8    = (u8*)(ws + 4194304);                    // 4 MB
    float* s_row = (float*)(ws + 8388608);                 // 64 KB
    float* s_col = (float*)(ws + 8388608 + 65536);         // 64 KB
    float* diag  = (float*)(ws + 8388608 + 131072);        // 64 KB
    float* out   = (float*)d_out;

    prep_kernel<<<1024, 256, 0, stream>>>(img, txt, A8, B8, s_row, out);
    gemm_lse_kernel<<<1024, 256, 0, stream>>>(A8, B8, s_row, s_col, diag);
    final_kernel<<<64, 256, 0, stream>>>(s_row, s_col, diag, out);
}

// Round 17
// 144.314 us; speedup vs baseline: 2.2117x; 2.2117x over previous
//
#include <hip/hip_runtime.h>
#include <hip/hip_bf16.h>

#define NN 16384
#define DD 256

typedef unsigned short u16;
typedef unsigned int u32;
typedef unsigned char u8;
typedef long i64;
typedef __attribute__((ext_vector_type(4))) float f32x4;
typedef __attribute__((ext_vector_type(4))) int i32x4;
typedef __attribute__((ext_vector_type(8))) int i32x8;

// ---------- kernel 1: fp8 e4m3 convert, LDS-transposed, all-coalesced ----------
// (verbatim from R6 -- measured clean, absmax 0.)
// A8 and B8 share ONE fragment-linear layout:
//   addr = pn<<15 | k2<<14 | r8<<11 | jj<<10 | qq<<8 | mm<<4 | u
//   holding fp8 of row (pn*128 + r8*16 + mm), kbyte (k2*128 + qq*32 + jj*16 + u).
__global__ __launch_bounds__(256) void prep_kernel(
        const float* __restrict__ img, const float* __restrict__ txt,
        u8* __restrict__ A8, u8* __restrict__ B8,
        float* __restrict__ zbuf /* s_row..s_col 32768 f */,
        float* __restrict__ out) {
    __shared__ u32 sA[16 * 65 + 8];
    __shared__ u32 sB[16 * 65 + 8];
    const int t = threadIdx.x, bi = blockIdx.x;            // bi = 16-row window
    const float4* ib = (const float4*)img + ((size_t)bi << 10);
    const float4* tb = (const float4*)txt + ((size_t)bi << 10);
    const float S = 1.44269504088896f;                     // log2(e) folded into A
    #pragma unroll
    for (int k = 0; k < 4; ++k) {
        const int idx = (k << 8) + t;                      // 0..1023 float4s
        const int row = idx >> 6, col = idx & 63;          // row 0..15, col 0..63
        float4 va = ib[idx];
        int pa = __builtin_amdgcn_cvt_pk_fp8_f32(va.x * S, va.y * S, 0, false);
        pa     = __builtin_amdgcn_cvt_pk_fp8_f32(va.z * S, va.w * S, pa, true);
        sA[row * 65 + col] = (u32)pa;
        float4 vb = tb[idx];
        int pb = __builtin_amdgcn_cvt_pk_fp8_f32(vb.x, vb.y, 0, false);
        pb     = __builtin_amdgcn_cvt_pk_fp8_f32(vb.z, vb.w, pb, true);
        sB[row * 65 + col] = (u32)pb;
    }
    __syncthreads();
    const int w = t >> 6, l = t & 63;
    const int k2 = w >> 1, jj = w & 1, qq = l >> 4, mm = l & 15;
    const int wb = mm * 65 + (k2 << 5) + (qq << 3) + (jj << 2);
    i32x4 oa = { (int)sA[wb], (int)sA[wb + 1], (int)sA[wb + 2], (int)sA[wb + 3] };
    i32x4 ob = { (int)sB[wb], (int)sB[wb + 1], (int)sB[wb + 2], (int)sB[wb + 3] };
    const size_t dst = ((size_t)(bi >> 3) << 15) + (k2 << 14) + ((size_t)(bi & 7) << 11)
                     + (jj << 10) + (qq << 8) + (mm << 4);
    *(i32x4*)(A8 + dst) = oa;
    *(i32x4*)(B8 + dst) = ob;
    const int gid = (bi << 8) + t;
    if (gid < 32768) zbuf[gid] = 0.0f;
    if (gid == 0) out[0] = 0.0f;
}

// ---------- kernel 2: MX-scaled fp8 GEMM + exp2 + row/col sum + diag ----------
// EXACT R14 (session best: total 143.8 us, gemm 78.2, clean counters).
// R16 closed the occupancy x register matrix: (256,3) evicted the acc banks
// to scratch (VGPR 84, FETCH 444 MB, 260 us). Every cell off this point is
// measured worse: R7/R9 reg-pipeline -> spill; R10 4wv split -> spill;
// R13 SGB pinning -> -15%; R14 skew -> neutral (kept, harmless); R15
// producer/consumer -> -32%. Structural constraint: areg 64 + acc 64 = 172
// regs/wave floor at this tile shape -> 2 waves/SIMD; per-wave dep chain
// (acc -> exp2 -> reduce -> same acc bank reused) serializes MFMA and VALU
// pipes; all plain-HIP levers to break it are measured and rejected.
__global__ __launch_bounds__(256, 2) void gemm_lse_kernel(
        const u8* __restrict__ A8, const u8* __restrict__ B8,
        float* __restrict__ s_row, float* __restrict__ s_col,
        float* __restrict__ diag) {
    // ---- anti-phase skew (R14: neutral, kept for exact reproduction) ----
    if ((blockIdx.x >> 8) & 1) {
        __builtin_amdgcn_s_sleep(15);
        __builtin_amdgcn_s_sleep(15);
        __builtin_amdgcn_s_sleep(15);
    }

    const int t = threadIdx.x;
    const int lane = t & 63;
    const int w = t >> 6;
    const int wr = w >> 1, wc = w & 1;
    const int q = lane >> 4, m = lane & 15;
    const int bi = blockIdx.x & 127;
    const int jg = blockIdx.x >> 7;
    const int row0 = bi << 7;

    // ---- A fragments direct from global (fragment-linear, coalesced) ----
    const u8* Aw = A8 + ((size_t)bi << 15) + ((size_t)lane << 4);
    i32x8 areg[2][4];
    #pragma unroll
    for (int k2 = 0; k2 < 2; ++k2)
        #pragma unroll
        for (int rb = 0; rb < 4; ++rb) {
            const u8* p = Aw + (k2 << 14) + (((wr << 2) + rb) << 11);
            i32x4 lo = *(const i32x4*)(p);
            i32x4 hi = *(const i32x4*)(p + 1024);
            areg[k2][rb] = __builtin_shufflevector(lo, hi, 0, 1, 2, 3, 4, 5, 6, 7);
        }

    const f32x4 fzero = {0.f, 0.f, 0.f, 0.f};
    f32x4 accA[4][2], accB[4][2];                 // half-tile acc banks (static)
    f32x4 rp[4] = {fzero, fzero, fzero, fzero};   // row partials
    float cpartT = 0.0f;                          // per-tile col partial

    const u8* Bw = B8 + (wc << 13) + ((size_t)lane << 4);

    i32x8 bf0, bf1, bf2, bf3;   // rotating one-fragment banks (slot i&3)

    // load fragment for slot ii (ii in 0..7: h=ii>>2, k2=(ii>>1)&1, cbl=ii&1)
    auto load_slot = [&](i32x8& bank, int jt_, int ii) {
        const int ct = (jg << 4) | ((jt_ + bi) & 15);
        const u8* pp = Bw + ((size_t)ct << 15) + ((ii >> 2) << 12)
                     + (((ii >> 1) & 1) << 14) + ((ii & 1) << 11);
        i32x4 lo = *(const i32x4*)(pp);
        i32x4 hi = *(const i32x4*)(pp + 1024);
        bank = __builtin_shufflevector(lo, hi, 0, 1, 2, 3, 4, 5, 6, 7);
    };

    // 4 MFMAs of one slot (k2_, cbl_ are call-site literals -> static acc idx)
    auto mfma_slot = [&](f32x4 (&acc)[4][2], const i32x8& bank, int k2_, int cbl_) {
        const f32x4 cinit = {-144.f, -144.f, -144.f, -144.f}; // exp2 bias in C
        if (k2_ == 0) {
            #pragma unroll
            for (int rb = 0; rb < 4; ++rb)
                acc[rb][cbl_] = __builtin_amdgcn_mfma_scale_f32_16x16x128_f8f6f4(
                    areg[0][rb], bank, cinit, 0, 0, 0, 127, 0, 127);
        } else {
            #pragma unroll
            for (int rb = 0; rb < 4; ++rb)
                acc[rb][cbl_] = __builtin_amdgcn_mfma_scale_f32_16x16x128_f8f6f4(
                    areg[1][rb], bank, acc[rb][cbl_], 0, 0, 0, 127, 0, 127);
        }
    };

    // epilogue for a finished half (diag, exp2, row/col partials)
    auto epilogue_half = [&](f32x4 (&acc)[4][2], int jt_, int h) {
        const int ct = (jg << 4) | ((jt_ + bi) & 15);
        if (bi == ct && wr == wc) {
            #pragma unroll
            for (int rb = 0; rb < 4; ++rb)
                if ((rb >> 1) == h) {
                    #pragma unroll
                    for (int r = 0; r < 4; ++r)
                        if (m == ((q << 2) | r))
                            diag[row0 + (wr << 6) + (rb << 4) + m] = acc[rb][rb & 1][r];
                }
        }
        #pragma unroll
        for (int rb = 0; rb < 4; ++rb)
            #pragma unroll
            for (int cb = 0; cb < 2; ++cb)
                #pragma unroll
                for (int r = 0; r < 4; ++r)
                    acc[rb][cb][r] = __builtin_amdgcn_exp2f(acc[rb][cb][r]);
        #pragma unroll
        for (int rb = 0; rb < 4; ++rb)
            rp[rb] += acc[rb][0] + acc[rb][1];
        #pragma unroll
        for (int cb = 0; cb < 2; ++cb) {
            f32x4 s = (acc[0][cb] + acc[1][cb]) + (acc[2][cb] + acc[3][cb]);
            float v = (s[0] + s[1]) + (s[2] + s[3]);
            v += __shfl_xor(v, 16, 64);
            v += __shfl_xor(v, 32, 64);
            if (q == ((h << 1) | cb)) cpartT = v;
        }
        if (h == 1) {
            const int col0 = ct << 7;
            atomicAdd(&s_col[col0 + (wc << 6) + (q << 4) + m], cpartT);
        }
    };

    // ---- rotating-prefetch main loop: load slot s+2 at slot s ----
    load_slot(bf0, 0, 0);
    load_slot(bf1, 0, 1);
    #pragma unroll 1
    for (int jt = 0; jt < 16; ++jt) {
        load_slot(bf2, jt, 2);  mfma_slot(accA, bf0, 0, 0);   // slot 0
        load_slot(bf3, jt, 3);  mfma_slot(accA, bf1, 0, 1);   // slot 1
        load_slot(bf0, jt, 4);  mfma_slot(accA, bf2, 1, 0);   // slot 2
        load_slot(bf1, jt, 5);  mfma_slot(accA, bf3, 1, 1);   // slot 3
        if (jt > 0) epilogue_half(accB, jt - 1, 1);
        load_slot(bf2, jt, 6);  mfma_slot(accB, bf0, 0, 0);   // slot 4
        load_slot(bf3, jt, 7);  mfma_slot(accB, bf1, 0, 1);   // slot 5
        if (jt < 15) load_slot(bf0, jt + 1, 0);
        mfma_slot(accB, bf2, 1, 0);                           // slot 6
        if (jt < 15) load_slot(bf1, jt + 1, 1);
        mfma_slot(accB, bf3, 1, 1);                           // slot 7
        epilogue_half(accA, jt, 0);
    }
    epilogue_half(accB, 15, 1);

    // ---- block-end row reduction ----
    float rout = 0.0f;
    #pragma unroll
    for (int rb = 0; rb < 4; ++rb)
        #pragma unroll
        for (int r = 0; r < 4; ++r) {
            float v = rp[rb][r];
            v += __shfl_xor(v, 1, 16);
            v += __shfl_xor(v, 2, 16);
            v += __shfl_xor(v, 4, 16);
            v += __shfl_xor(v, 8, 16);
            if (m == ((rb << 2) | r)) rout = v;
        }
    atomicAdd(&s_row[row0 + (wr << 6) + ((m >> 2) << 4) + (q << 2) + (m & 3)], rout);
}

// ---------- kernel 3: final reduce (64 blocks, 256 rows each) ----------
// diag is biased by -144; the +144 LSE un-bias cancels it exactly.
__global__ void final_kernel(const float* __restrict__ s_row, const float* __restrict__ s_col,
                             const float* __restrict__ diag, float* __restrict__ out) {
    __shared__ double red[256];
    int t = threadIdx.x;
    int i = blockIdx.x * 256 + t;
    double p = 0.5 * (double)(log2f(s_row[i]) + log2f(s_col[i])) - (double)diag[i];
    red[t] = p;
    __syncthreads();
    for (int s = 128; s > 0; s >>= 1) {
        if (t < s) red[t] += red[t + s];
        __syncthreads();
    }
    if (t == 0) atomicAdd(out, (float)(red[0] * 0.6931471805599453 / (double)NN));
}

// ---------- launch ----------
extern "C" void kernel_launch(void* const* d_in, const int* in_sizes, int n_in,
                              void* d_out, int out_size, void* d_ws, size_t ws_size,
                              hipStream_t stream) {
    const float* img = (const float*)d_in[0];
    const float* txt = (const float*)d_in[1];
    char* ws = (char*)d_ws;
    u8*    A8    = (u8*)ws;                                // 4 MB
    u8*    B8    = (u8*)(ws + 4194304);                    // 4 MB
    float* s_row = (float*)(ws + 8388608);                 // 64 KB
    float* s_col = (float*)(ws + 8388608 + 65536);         // 64 KB
    float* diag  = (float*)(ws + 8388608 + 131072);        // 64 KB
    float* out   = (float*)d_out;

    prep_kernel<<<1024, 256, 0, stream>>>(img, txt, A8, B8, s_row, out);
    gemm_lse_kernel<<<1024, 256, 0, stream>>>(A8, B8, s_row, s_col, diag);
    final_kernel<<<64, 256, 0, stream>>>(s_row, s_col, diag, out);
}